// Round 5
// baseline (20817.189 us; speedup 1.0000x reference)
//
#include <hip/hip_runtime.h>
#include <stdint.h>
#include <stddef.h>

// PowerLawLayer RNN, MI355X persistent-kernel, R5.
//
// R1: 1024-thr wg => 128-VGPR cap, alloc 64 => full weight spill, 39 ms.
// R2: 512-thr wg => alloc 128, demand ~180 => 27 GB spill FETCH, 44 ms.
// R3: amdgpu_waves_per_eu(2,2) ignored (same spill), 44 ms.
// R4: demand under cap (72 w-floats/thread): spill gone (VGPR 84, FETCH
//     130 MB) => 20 ms. But VALUBusy 11.7%, 46k cyc/step vs 2.3k FMA floor:
//     ctr[0..7] in ONE cacheline => 256 same-line atomic RMWs + spin loads
//     per step serialize at the LLC (~36k cyc) — a global convoy.
// R5: one-sided per-wg progress flags, zero RMW: producer release-stores
//     progress[g*32+s]=t+1 (distinct addresses, 128 B per group); wave-0
//     lanes spin on one coalesced 128-B load of the group's 32 flags.
//     Ping-pong safe at any skew: entering step t+1 requires all peers
//     posted t+1, which happens only after they finished READING buf[t&1].
//
//   wg = (16 j's) x (full k=768) x (8 batches); 256 wgs = 32 slices x 8
//   batch groups; group g = bid&7 (XCD co-location heuristic; atomics keep
//   it correct regardless). 576 FMA/thread/step = per-SIMD floor 2304 cyc.
//
// Workspace: hbuf[2][64][512] f32 + progress[256] u32 = 263,168 B.

#define Hh   512
#define Tt   1024
#define Bb   64
#define II   256
#define EPSc 0.001f
#define PV   0.2f

__global__ __launch_bounds__(1024) void plr_init(float* hbuf, unsigned* progress) {
  int idx = blockIdx.x * blockDim.x + threadIdx.x;
  if (idx < Bb * Hh) hbuf[idx] = 0.0f;        // h(0) = 0 in buffer 0
  if (idx < 256) progress[idx] = 0u;          // per-wg progress flags
}

__global__ __launch_bounds__(512, 3)
void plr_main(
    const float* __restrict__ x,    // [B, T, I]
    const float* __restrict__ Wih,  // [3H, I]
    const float* __restrict__ Whh,  // [3H, H]
    const float* __restrict__ bias, // [3H]
    float* __restrict__ out,        // [B,T,H] ++ h_f ++ c_f ++ k_f
    float* hbuf,                    // [2][B][H]
    unsigned* progress)             // [256] = [group][peer]
{
  __shared__ float h_tile[8 * Hh];        // [bl][k]      16 KB
  __shared__ float x_tile[2 * 8 * II];    // [buf][bl][k] 16 KB
  __shared__ float part[3264];            // ((gi*8+bl)*8+w)*17 + jj  12.8 KB

  const int tid = threadIdx.x;
  const int w   = tid >> 6;          // wave 0..7
  const int l   = tid & 63;
  const int jj  = l & 15;            // hidden offset within slice
  const int kl  = (l >> 4) & 3;      // k sub-chunk within wave
  const int kc  = (w << 2) | kl;     // k-chunk 0..31
  const int bid = blockIdx.x;
  const int g   = bid & 7;           // batch group == XCD (round-robin)
  const int s   = bid >> 3;          // hidden slice / peer id 0..31
  const int j0  = s * 16;
  const int b0  = g * 8;

  // ---- one-time: weights into registers (72 floats/thread) ------------
  float whh[3][16];
  float wih[3][8];
#pragma unroll
  for (int gi = 0; gi < 3; ++gi) {
    const int row = gi * Hh + j0 + jj;
    const float4* ph = (const float4*)(Whh + (size_t)row * Hh + kc * 16);
#pragma unroll
    for (int i = 0; i < 4; ++i) {
      float4 v = ph[i];
      whh[gi][4*i+0] = v.x; whh[gi][4*i+1] = v.y;
      whh[gi][4*i+2] = v.z; whh[gi][4*i+3] = v.w;
    }
    const float4* pi = (const float4*)(Wih + (size_t)row * II + kc * 8);
#pragma unroll
    for (int i = 0; i < 2; ++i) {
      float4 v = pi[i];
      wih[gi][4*i+0] = v.x; wih[gi][4*i+1] = v.y;
      wih[gi][4*i+2] = v.z; wih[gi][4*i+3] = v.w;
    }
  }

  // ---- updater state (threads 0..127: br = tid>>4, jr = tid&15) -------
  float c_st = 0.0f, k_st = -1.0f;
  float bia0 = 0.f, bia1 = 0.f, bia2 = 0.f;
  if (tid < 128) {
    const int jr = tid & 15;
    bia0 = bias[0 * Hh + j0 + jr];
    bia1 = bias[1 * Hh + j0 + jr];
    bia2 = bias[2 * Hh + j0 + jr];
  }

  // ---- prologue: stage x(0) -------------------------------------------
  {
    const int bl = tid >> 6, k4 = (tid & 63) * 4;
    *(float4*)(x_tile + bl * II + k4) =
        *(const float4*)(x + ((size_t)(b0 + bl) * Tt + 0) * II + k4);
  }

  bool broken = false;  // bounded-spin escape (never taken when co-resident)

  for (int t = 0; t < Tt; ++t) {
    // ---- stage h(t) from LLC (visibility guaranteed by flag spin) ------
    {
      const float* hb = hbuf + (size_t)(t & 1) * Bb * Hh + (size_t)b0 * Hh;
#pragma unroll
      for (int i = 0; i < 8; ++i)
        h_tile[i * Hh + tid] = __hip_atomic_load(
            hb + i * Hh + tid, __ATOMIC_RELAXED, __HIP_MEMORY_SCOPE_AGENT);
    }
    __syncthreads();  // (A) h_tile + x_tile ready

    // ---- gemv: 576 FMA/thread in 2 passes of 4 batches -----------------
    const float* xt = x_tile + (t & 1) * 8 * II;
#pragma unroll
    for (int pass = 0; pass < 2; ++pass) {
      float acc[3][4];
#pragma unroll
      for (int b4 = 0; b4 < 4; ++b4) {
        const int bl = pass * 4 + b4;
        const float4* h4 = (const float4*)(h_tile + bl * Hh) + kc * 4;
        const float4* x4 = (const float4*)(xt + bl * II) + kc * 2;
        float a0 = 0.f, a1 = 0.f, a2 = 0.f;
#pragma unroll
        for (int i = 0; i < 4; ++i) {
          float4 hv = h4[i];
          a0 = fmaf(whh[0][4*i+0], hv.x, a0); a0 = fmaf(whh[0][4*i+1], hv.y, a0);
          a0 = fmaf(whh[0][4*i+2], hv.z, a0); a0 = fmaf(whh[0][4*i+3], hv.w, a0);
          a1 = fmaf(whh[1][4*i+0], hv.x, a1); a1 = fmaf(whh[1][4*i+1], hv.y, a1);
          a1 = fmaf(whh[1][4*i+2], hv.z, a1); a1 = fmaf(whh[1][4*i+3], hv.w, a1);
          a2 = fmaf(whh[2][4*i+0], hv.x, a2); a2 = fmaf(whh[2][4*i+1], hv.y, a2);
          a2 = fmaf(whh[2][4*i+2], hv.z, a2); a2 = fmaf(whh[2][4*i+3], hv.w, a2);
        }
#pragma unroll
        for (int i = 0; i < 2; ++i) {
          float4 xv = x4[i];
          a0 = fmaf(wih[0][4*i+0], xv.x, a0); a0 = fmaf(wih[0][4*i+1], xv.y, a0);
          a0 = fmaf(wih[0][4*i+2], xv.z, a0); a0 = fmaf(wih[0][4*i+3], xv.w, a0);
          a1 = fmaf(wih[1][4*i+0], xv.x, a1); a1 = fmaf(wih[1][4*i+1], xv.y, a1);
          a1 = fmaf(wih[1][4*i+2], xv.z, a1); a1 = fmaf(wih[1][4*i+3], xv.w, a1);
          a2 = fmaf(wih[2][4*i+0], xv.x, a2); a2 = fmaf(wih[2][4*i+1], xv.y, a2);
          a2 = fmaf(wih[2][4*i+2], xv.z, a2); a2 = fmaf(wih[2][4*i+3], xv.w, a2);
        }
        acc[0][b4] = a0; acc[1][b4] = a1; acc[2][b4] = a2;
      }
      // reduce the 4 kl sub-chunks in-register, one masked store per combo
#pragma unroll
      for (int gi = 0; gi < 3; ++gi)
#pragma unroll
        for (int b4 = 0; b4 < 4; ++b4) {
          float v = acc[gi][b4];
          v += __shfl_xor(v, 16, 64);
          v += __shfl_xor(v, 32, 64);
          if (l < 16)
            part[((gi * 8 + pass * 4 + b4) * 8 + w) * 17 + jj] = v;
        }
    }

    // ---- stage x(t+1) during the gap (independent of h exchange) -------
    if (t + 1 < Tt) {
      const int bl = tid >> 6, k4 = (tid & 63) * 4;
      *(float4*)(x_tile + ((t + 1) & 1) * 8 * II + bl * II + k4) =
          *(const float4*)(x + ((size_t)(b0 + bl) * Tt + (t + 1)) * II + k4);
    }
    __syncthreads();  // (B) partials visible

    // ---- reduce + elementwise + h store (threads 0..127) ---------------
    float hn = 0.f, cn = 0.f, kn = 0.f;
    if (tid < 128) {
      const int jr = tid & 15, br = tid >> 4;
      float s0 = bia0, s1 = bia1, s2 = bia2;
#pragma unroll
      for (int ww = 0; ww < 8; ++ww) {
        s0 += part[((0 * 8 + br) * 8 + ww) * 17 + jr];
        s1 += part[((1 * 8 + br) * 8 + ww) * 17 + jr];
        s2 += part[((2 * 8 + br) * 8 + ww) * 17 + jr];
      }
      const float tf = (float)t;
      const float r  = 1.0f / (1.0f + __expf(-s0));
      const float o  = 1.0f / (1.0f + __expf(-s1));
      const float gg = 1.0f - 2.0f / (1.0f + __expf(2.0f * s2));
      kn = r * (tf - EPSc) + (1.0f - r) * k_st;
      const float d  = tf - kn;
      const float f  = __expf(PV * __logf((d + EPSc) / (d + 1.0f)));
      cn = f * c_st + (1.0f - f) * gg;
      hn = o * (1.0f - 2.0f / (1.0f + __expf(2.0f * cn)));
      c_st = cn; k_st = kn;
      __hip_atomic_store(
          hbuf + (size_t)((t + 1) & 1) * Bb * Hh + (size_t)(b0 + br) * Hh +
              j0 + jr,
          hn, __ATOMIC_RELAXED, __HIP_MEMORY_SCOPE_AGENT);
    }
    __syncthreads();  // (C) drains hbuf stores before the flag release

    // ---- publish progress (plain store, no RMW), then out[] stores -----
    if (tid == 0)
      __hip_atomic_store(progress + (g << 5) + s, (unsigned)(t + 1),
                         __ATOMIC_RELEASE, __HIP_MEMORY_SCOPE_AGENT);
    if (tid < 128) {
      const int jr = tid & 15, br = tid >> 4;
      const int b = b0 + br, j = j0 + jr;
      out[((size_t)b * Tt + t) * Hh + j] = hn;
      if (t == Tt - 1) {
        const size_t base = (size_t)Bb * Tt * Hh;
        out[base + 0 * Bb * Hh + (size_t)b * Hh + j] = hn;  // h_f
        out[base + 1 * Bb * Hh + (size_t)b * Hh + j] = cn;  // c_f
        out[base + 2 * Bb * Hh + (size_t)b * Hh + j] = kn;  // k_f
      }
    }

    // ---- wait for all 32 peers to publish t+1 (coalesced flag load) ----
    if (t < Tt - 1) {
      if (w == 0 && !broken) {
        const unsigned target = (unsigned)(t + 1);
        const unsigned* pf = progress + (g << 5);
        int it = 0;
        for (;;) {
          unsigned v = 0xFFFFFFFFu;
          if (l < 32)
            v = __hip_atomic_load(pf + l, __ATOMIC_ACQUIRE,
                                  __HIP_MEMORY_SCOPE_AGENT);
          unsigned long long bal = __ballot(v >= target);
          if (bal == ~0ull) break;
          __builtin_amdgcn_s_sleep(1);
          if (++it > (1 << 22)) { broken = true; break; }
        }
      }
      __syncthreads();  // (D) everyone proceeds once wave 0 confirms
    }
  }
}

extern "C" void kernel_launch(void* const* d_in, const int* in_sizes, int n_in,
                              void* d_out, int out_size, void* d_ws, size_t ws_size,
                              hipStream_t stream) {
  const float* x    = (const float*)d_in[0];
  const float* Wih  = (const float*)d_in[1];
  const float* Whh  = (const float*)d_in[2];
  const float* bias = (const float*)d_in[3];
  float* out = (float*)d_out;

  float*    hbuf     = (float*)d_ws;                              // 2*64*512 f32
  unsigned* progress = (unsigned*)((char*)d_ws + 2 * Bb * Hh * sizeof(float));

  plr_init<<<32, 1024, 0, stream>>>(hbuf, progress);
  plr_main<<<256, 512, 0, stream>>>(x, Wih, Whh, bias, out, hbuf, progress);
}